// Round 18
// baseline (693.047 us; speedup 1.0000x reference)
//
#include <hip/hip_runtime.h>

// MixTransformerBlock on MI355X (gfx950).
// Round 18: R17 + byte-diet on proj residual (bf16 x/y copies from ln_dual,
// proj reads 134MB bf16 instead of 268MB f32 — R8-R12 proved this error-free)
// + GELU constant folding in fc1 epilogue. GEMM structures frozen.

typedef __attribute__((ext_vector_type(8))) short bf16x8;
typedef __attribute__((ext_vector_type(4))) float f32x4;

#define NTOK 32768   // B * H * W
#define CDIM 512

__device__ __forceinline__ unsigned short f2bf(float f) {
  unsigned int u = __float_as_uint(f);
  u = (u + 0x7fffu + ((u >> 16) & 1u)) >> 16;   // RNE (inputs finite)
  return (unsigned short)u;
}
__device__ __forceinline__ float bf2f(unsigned short u) {
  return __uint_as_float(((unsigned int)u) << 16);
}

__device__ __forceinline__ void gload_lds16(const void* g, void* l) {
  __builtin_amdgcn_global_load_lds(
      (const __attribute__((address_space(1))) void*)g,
      (__attribute__((address_space(3))) void*)l, 16, 0, 0);
}

// ---------------------------------------------------------------- transpose
struct TpArgs { const float* W[4]; unsigned short* O[4]; };

__global__ __launch_bounds__(256)
void transpose_w(TpArgs ta, int K, int N) {
  __shared__ float tile[64][65];
  const float* __restrict__ W = ta.W[blockIdx.z];
  unsigned short* __restrict__ Wt = ta.O[blockIdx.z];
  const int n0 = blockIdx.x * 64, k0 = blockIdx.y * 64;
  const int c = threadIdx.x & 63, rb = threadIdx.x >> 6;
#pragma unroll
  for (int i = 0; i < 16; ++i) {
    int r = i * 4 + rb;
    tile[r][c] = W[(long)(k0 + r) * N + n0 + c];
  }
  __syncthreads();
#pragma unroll
  for (int i = 0; i < 16; ++i) {
    int rn = i * 4 + rb;
    Wt[(long)(n0 + rn) * K + k0 + c] = f2bf(tile[c][rn]);
  }
}

struct Tp8Args { const float* W[4]; unsigned char* O[4]; };

__global__ __launch_bounds__(256)
void transpose_w8(Tp8Args ta, int K, int N) {
  __shared__ float tile[64][65];
  const float* __restrict__ W = ta.W[blockIdx.z];
  unsigned char* __restrict__ Wt = ta.O[blockIdx.z];
  const int n0 = blockIdx.x * 64, k0 = blockIdx.y * 64;
  const int c = threadIdx.x & 63, rb = threadIdx.x >> 6;
#pragma unroll
  for (int i = 0; i < 16; ++i) {
    int r = i * 4 + rb;
    tile[r][c] = W[(long)(k0 + r) * N + n0 + c];
  }
  __syncthreads();
#pragma unroll
  for (int i = 0; i < 16; ++i) {
    int rn = i * 4 + rb;
    const float v = tile[c][rn];
    int p = __builtin_amdgcn_cvt_pk_fp8_f32(v, v, 0, false);
    Wt[(long)(n0 + rn) * K + k0 + c] = (unsigned char)(p & 0xff);
  }
}

// ---------------------------------------------------------------- bias pack
__global__ __launch_bounds__(256)
void pack_bias(const float* bkv0, const float* bq0,
               const float* bkv1, const float* bq1,
               float* o0, float* o1) {
  const int i = blockIdx.x * 256 + threadIdx.x;   // 0..1535
  o0[i] = (i < 1024) ? bkv0[i] : bq0[i - 1024];
  o1[i] = (i < 1024) ? bkv1[i] : bq1[i - 1024];
}

// ---------------------------------------------------------------- layernorms
// f32 in -> LN bf16 out + raw bf16 copy; blockIdx.y selects x/y side.
__global__ __launch_bounds__(256)
void ln_dual(const float* X0, const float* X1,
             const float* g0_, const float* b0_,
             const float* g1_, const float* b1_,
             unsigned short* oln0, unsigned short* oln1,
             unsigned short* oraw0, unsigned short* oraw1) {
  const int zz = blockIdx.y;
  const float* __restrict__ X = zz ? X1 : X0;
  const float* __restrict__ g = zz ? g1_ : g0_;
  const float* __restrict__ b = zz ? b1_ : b0_;
  unsigned short* __restrict__ outln = zz ? oln1 : oln0;
  unsigned short* __restrict__ outraw = zz ? oraw1 : oraw0;

  const int lane = threadIdx.x & 63;
  const int wid = threadIdx.x >> 6;
  const long t = (long)blockIdx.x * 4 + wid;
  const float* x = X + t * CDIM + lane * 8;
  float4 v0 = *(const float4*)x;
  float4 v1 = *(const float4*)(x + 4);
  float s = v0.x + v0.y + v0.z + v0.w + v1.x + v1.y + v1.z + v1.w;
  float sq = v0.x * v0.x + v0.y * v0.y + v0.z * v0.z + v0.w * v0.w +
             v1.x * v1.x + v1.y * v1.y + v1.z * v1.z + v1.w * v1.w;
#pragma unroll
  for (int off = 32; off; off >>= 1) {
    s += __shfl_xor(s, off);
    sq += __shfl_xor(sq, off);
  }
  const float mean = s * (1.0f / 512.0f);
  const float var = sq * (1.0f / 512.0f) - mean * mean;
  const float rs = rsqrtf(var + 1e-4f);
  float4 g0 = *(const float4*)(g + lane * 8);
  float4 g1 = *(const float4*)(g + lane * 8 + 4);
  float4 b0 = *(const float4*)(b + lane * 8);
  float4 b1 = *(const float4*)(b + lane * 8 + 4);
  bf16x8 r, w;
  r[0] = (short)f2bf((v0.x - mean) * rs * g0.x + b0.x);  w[0] = (short)f2bf(v0.x);
  r[1] = (short)f2bf((v0.y - mean) * rs * g0.y + b0.y);  w[1] = (short)f2bf(v0.y);
  r[2] = (short)f2bf((v0.z - mean) * rs * g0.z + b0.z);  w[2] = (short)f2bf(v0.z);
  r[3] = (short)f2bf((v0.w - mean) * rs * g0.w + b0.w);  w[3] = (short)f2bf(v0.w);
  r[4] = (short)f2bf((v1.x - mean) * rs * g1.x + b1.x);  w[4] = (short)f2bf(v1.x);
  r[5] = (short)f2bf((v1.y - mean) * rs * g1.y + b1.y);  w[5] = (short)f2bf(v1.y);
  r[6] = (short)f2bf((v1.z - mean) * rs * g1.z + b1.z);  w[6] = (short)f2bf(v1.z);
  r[7] = (short)f2bf((v1.w - mean) * rs * g1.w + b1.w);  w[7] = (short)f2bf(v1.w);
  *(bf16x8*)(outln + t * CDIM + lane * 8) = r;
  *(bf16x8*)(outraw + t * CDIM + lane * 8) = w;
}

// bf16 in -> LN fp8 out (for LN2/LN4 feeding the fp8 fc1)
__global__ __launch_bounds__(256)
void ln_b16_f8(const unsigned short* X0, const unsigned short* X1,
               const float* g0_, const float* b0_,
               const float* g1_, const float* b1_,
               unsigned char* o0, unsigned char* o1) {
  const int zz = blockIdx.y;
  const unsigned short* __restrict__ X = zz ? X1 : X0;
  const float* __restrict__ g = zz ? g1_ : g0_;
  const float* __restrict__ b = zz ? b1_ : b0_;
  unsigned char* __restrict__ out = zz ? o1 : o0;

  const int lane = threadIdx.x & 63;
  const int wid = threadIdx.x >> 6;
  const long t = (long)blockIdx.x * 4 + wid;
  bf16x8 v = *(const bf16x8*)(X + t * CDIM + lane * 8);
  float f[8];
  float s = 0.f, sq = 0.f;
#pragma unroll
  for (int i = 0; i < 8; ++i) {
    f[i] = bf2f((unsigned short)v[i]);
    s += f[i]; sq += f[i] * f[i];
  }
#pragma unroll
  for (int off = 32; off; off >>= 1) {
    s += __shfl_xor(s, off);
    sq += __shfl_xor(sq, off);
  }
  const float mean = s * (1.0f / 512.0f);
  const float var = sq * (1.0f / 512.0f) - mean * mean;
  const float rs = rsqrtf(var + 1e-4f);
  float4 g0 = *(const float4*)(g + lane * 8);
  float4 g1 = *(const float4*)(g + lane * 8 + 4);
  float4 b0 = *(const float4*)(b + lane * 8);
  float4 b1 = *(const float4*)(b + lane * 8 + 4);
  const float gg[8] = {g0.x, g0.y, g0.z, g0.w, g1.x, g1.y, g1.z, g1.w};
  const float bb[8] = {b0.x, b0.y, b0.z, b0.w, b1.x, b1.y, b1.z, b1.w};
  float q[8];
#pragma unroll
  for (int i = 0; i < 8; ++i)
    q[i] = (f[i] - mean) * rs * gg[i] + bb[i];
  int w0 = __builtin_amdgcn_cvt_pk_fp8_f32(q[0], q[1], 0, false);
  w0 = __builtin_amdgcn_cvt_pk_fp8_f32(q[2], q[3], w0, true);
  int w1 = __builtin_amdgcn_cvt_pk_fp8_f32(q[4], q[5], 0, false);
  w1 = __builtin_amdgcn_cvt_pk_fp8_f32(q[6], q[7], w1, true);
  int2 pk; pk.x = w0; pk.y = w1;
  *(int2*)(out + t * CDIM + lane * 8) = pk;
}

// ---------------------------------------------------------------- GEMM 256x128 (bf16, R11)
// EPI 4: out bf16 (+bias), * scale for cols >= 1024      (fused kv|q)
// EPI 5: out bf16 (+bias + bf16 resid)                   (proj -> x1)

struct PairArgs {
  const void* A0; const void* A1;
  const void* B0; const void* B1;
  const float* bias0; const float* bias1;
  const void* r0; const void* r1;
  void* o0; void* o1;
};

template <int EPI>
__global__ __launch_bounds__(512, 4)
void gemm_mt(PairArgs pa, float scale, int M, int N, int K) {
  // LDS: A dbuf 2x32K | B 16K at 65536. Total 80 KB -> 2 blocks/CU.
  __shared__ __attribute__((aligned(16))) char lds[81920];

  const int z = blockIdx.z;
  const unsigned short* __restrict__ A  = (const unsigned short*)(z ? pa.A1 : pa.A0);
  const unsigned short* __restrict__ Bt = (const unsigned short*)(z ? pa.B1 : pa.B0);
  const float* __restrict__ bias = z ? pa.bias1 : pa.bias0;
  const void* resid = z ? pa.r1 : pa.r0;
  void* outp = z ? pa.o1 : pa.o0;

  // T1: bijective XCD-aware remap (m204 form)
  const int nwg = gridDim.x * gridDim.y;
  int wg = blockIdx.y * gridDim.x + blockIdx.x;
  {
    const int q8 = nwg >> 3, r8 = nwg & 7;
    const int xcd = wg & 7, o = wg >> 3;
    wg = (xcd < r8 ? xcd * (q8 + 1) : r8 * (q8 + 1) + (xcd - r8) * q8) + o;
  }
  const int bx = wg % gridDim.x, by = wg / gridDim.x;

  const int tid = threadIdx.x;
  const int lane = tid & 63;
  const int wid = tid >> 6;        // 0..7
  const int wr = wid >> 1;         // 0..3  (M quarter)
  const int wc = wid & 1;          // 0..1  (N half)
  const long rowBase = (long)by * 256;
  const long colBase = (long)bx * 128;

  const unsigned short* Ap = A + rowBase * K;
  const unsigned short* Bp = Bt + colBase * K;

  const int srow = tid >> 3;                     // 0..63
  const int sslot = (tid & 7) ^ (srow & 7);      // permuted 16B slot

  auto stA = [&](int buf, int k0, int i) {       // i = 0..3 (256 rows)
    gload_lds16(Ap + (long)(i * 64 + srow) * K + k0 + sslot * 8,
                lds + buf * 32768 + i * 8192 + tid * 16);
  };
  auto stB = [&](int k0, int i) {                // i = 0..1 (128 rows)
    gload_lds16(Bp + (long)(i * 64 + srow) * K + k0 + sslot * 8,
                lds + 65536 + i * 8192 + tid * 16);
  };

  const int lo = lane & 15;
  const int hi = lane >> 4;
  const int x7 = lane & 7;
  const int arow0 = (wr * 64 + lo) * 128;            // bytes within A buffer
  const int brow0 = 65536 + (wc * 64 + lo) * 128;    // bytes within B region

  f32x4 acc[4][4] = {};

  const int nt = K / 64;

  stA(0, 0, 0); stA(0, 0, 1); stA(0, 0, 2); stA(0, 0, 3);

  for (int t = 0; t < nt; ++t) {
    const int cur = t & 1;
    const int k0 = t * 64;
    const bool pf = (t + 1 < nt);

    stB(k0, 0); stB(k0, 1);
    if (pf) {
      const int k1 = k0 + 64;
      stA(cur ^ 1, k1, 0); stA(cur ^ 1, k1, 1);
      stA(cur ^ 1, k1, 2); stA(cur ^ 1, k1, 3);
      asm volatile("s_waitcnt vmcnt(4)" ::: "memory");   // A(t)+B(t) landed
    } else {
      asm volatile("s_waitcnt vmcnt(0)" ::: "memory");
    }
    __builtin_amdgcn_sched_barrier(0);
    __builtin_amdgcn_s_barrier();

#pragma unroll
    for (int kk = 0; kk < 2; ++kk) {
      const int cb = ((kk * 4 + hi) ^ x7) * 16;
      bf16x8 af[4], bf[4];
#pragma unroll
      for (int m = 0; m < 4; ++m)
        af[m] = *(const bf16x8*)(lds + cur * 32768 + arow0 + m * 2048 + cb);
#pragma unroll
      for (int n = 0; n < 4; ++n)
        bf[n] = *(const bf16x8*)(lds + brow0 + n * 2048 + cb);
#pragma unroll
      for (int m = 0; m < 4; ++m)
#pragma unroll
        for (int n = 0; n < 4; ++n)
          acc[m][n] = __builtin_amdgcn_mfma_f32_16x16x32_bf16(af[m], bf[n], acc[m][n], 0, 0, 0);
    }
    if (pf) __builtin_amdgcn_s_barrier();
  }

  // -------- epilogue
#pragma unroll
  for (int m = 0; m < 4; ++m) {
    const long rbase = rowBase + wr * 64 + m * 16 + hi * 4;
#pragma unroll
    for (int n = 0; n < 4; ++n) {
      const long col = colBase + wc * 64 + n * 16 + lo;
      const float bv = bias[col];
#pragma unroll
      for (int r = 0; r < 4; ++r) {
        float v = acc[m][n][r] + bv;
        const long idx = (rbase + r) * (long)N + col;
        if constexpr (EPI == 4) {
          if (col >= 1024) v *= scale;
          ((unsigned short*)outp)[idx] = f2bf(v);
        } else if constexpr (EPI == 5) {
          ((unsigned short*)outp)[idx] =
              f2bf(v + bf2f(((const unsigned short*)resid)[idx]));
        } else {
          ((unsigned short*)outp)[idx] = f2bf(v);
        }
      }
    }
  }
}

// ---------------------------------------------------------------- GEMM fp8
// BK=128, A-dbuf, R11 structure. ds_read = b64 (R15 form).
// EPI 2: out fp8 gelu_tanh(+bias)       (fc1)
// EPI 6: out f32 (+bias + bf16 resid)   (fc2)
template <int EPI>
__global__ __launch_bounds__(512, 4)
void gemm_f8(PairArgs pa, int M, int N, int K) {
  // LDS: A dbuf 2x32K | B 16K at 65536. 80 KB -> 2 blocks/CU.
  __shared__ __attribute__((aligned(16))) char lds[81920];

  const int z = blockIdx.z;
  const unsigned char* __restrict__ A  = (const unsigned char*)(z ? pa.A1 : pa.A0);
  const unsigned char* __restrict__ Bt = (const unsigned char*)(z ? pa.B1 : pa.B0);
  const float* __restrict__ bias = z ? pa.bias1 : pa.bias0;
  const unsigned short* __restrict__ resid =
      (const unsigned short*)(z ? pa.r1 : pa.r0);
  void* outp = z ? pa.o1 : pa.o0;

  const int nwg = gridDim.x * gridDim.y;
  int wg = blockIdx.y * gridDim.x + blockIdx.x;
  {
    const int q8 = nwg >> 3, r8 = nwg & 7;
    const int xcd = wg & 7, o = wg >> 3;
    wg = (xcd < r8 ? xcd * (q8 + 1) : r8 * (q8 + 1) + (xcd - r8) * q8) + o;
  }
  const int bx = wg % gridDim.x, by = wg / gridDim.x;

  const int tid = threadIdx.x;
  const int lane = tid & 63;
  const int wid = tid >> 6;
  const int wr = wid >> 1;         // 0..3
  const int wc = wid & 1;          // 0..1
  const long rowBase = (long)by * 256;
  const long colBase = (long)bx * 128;

  const unsigned char* Ap = A + rowBase * K;
  const unsigned char* Bp = Bt + colBase * K;

  const int srow = tid >> 3;                     // 0..63
  const int schunk = ((tid & 7) ^ (srow & 7)) * 16;   // byte offset in row

  auto stA = [&](int buf, int k0, int i) {       // i=0..3 (256 rows)
    gload_lds16(Ap + (long)(i * 64 + srow) * K + k0 + schunk,
                lds + buf * 32768 + i * 8192 + tid * 16);
  };
  auto stB = [&](int k0, int i) {                // i=0..1 (128 rows)
    gload_lds16(Bp + (long)(i * 64 + srow) * K + k0 + schunk,
                lds + 65536 + i * 8192 + tid * 16);
  };

  const int lo = lane & 15;
  const int hi = lane >> 4;
  const int arow0 = (wr * 64 + lo) * 128;
  const int brow0 = 65536 + (wc * 64 + lo) * 128;

  f32x4 acc[4][4] = {};

  const int nt = K / 128;

  stA(0, 0, 0); stA(0, 0, 1); stA(0, 0, 2); stA(0, 0, 3);

  for (int t = 0; t < nt; ++t) {
    const int cur = t & 1;
    const int k0 = t * 128;
    const bool pf = (t + 1 < nt);

    stB(k0, 0); stB(k0, 1);
    if (pf) {
      const int k1 = k0 + 128;
      stA(cur ^ 1, k1, 0); stA(cur ^ 1, k1, 1);
      stA(cur ^ 1, k1, 2); stA(cur ^ 1, k1, 3);
      asm volatile("s_waitcnt vmcnt(4)" ::: "memory");
    } else {
      asm volatile("s_waitcnt vmcnt(0)" ::: "memory");
    }
    __builtin_amdgcn_sched_barrier(0);
    __builtin_amdgcn_s_barrier();

#pragma unroll
    for (int kk = 0; kk < 4; ++kk) {
      // lane needs bytes [kk*32 + hi*8, +8) of its row, chunk-swizzled:
      const int cb = (((kk * 2 + (hi >> 1)) ^ (lo & 7)) * 16) + (hi & 1) * 8;
      long af[4], bq[4];
#pragma unroll
      for (int m = 0; m < 4; ++m)
        af[m] = *(const long*)(lds + cur * 32768 + arow0 + m * 2048 + cb);
#pragma unroll
      for (int n = 0; n < 4; ++n)
        bq[n] = *(const long*)(lds + brow0 + n * 2048 + cb);
#pragma unroll
      for (int m = 0; m < 4; ++m)
#pragma unroll
        for (int n = 0; n < 4; ++n)
          acc[m][n] = __builtin_amdgcn_mfma_f32_16x16x32_fp8_fp8(af[m], bq[n], acc[m][n], 0, 0, 0);
    }
    if (pf) __builtin_amdgcn_s_barrier();
  }

  // -------- epilogue
#pragma unroll
  for (int m = 0; m < 4; ++m) {
    const long rbase = rowBase + wr * 64 + m * 16 + hi * 4;
#pragma unroll
    for (int n = 0; n < 4; ++n) {
      const long col = colBase + wc * 64 + n * 16 + lo;
      const float bv = bias[col];
      if constexpr (EPI == 2) {
        float vv[4];
#pragma unroll
        for (int r = 0; r < 4; ++r) {
          float v = acc[m][n][r] + bv;
          // folded tanh-GELU: t = v*(c1 + c2*v^2); gelu = v*sigma(t)
          const float tt = v * (1.5957691216057308f + 0.07135481117848f * v * v);
          vv[r] = v * __fdividef(1.0f, 1.0f + __expf(-tt));
        }
        const int p01 = __builtin_amdgcn_cvt_pk_fp8_f32(vv[0], vv[1], 0, false);
        const int p23 = __builtin_amdgcn_cvt_pk_fp8_f32(vv[2], vv[3], 0, false);
        unsigned char* o8 = (unsigned char*)outp;
        o8[(rbase + 0) * (long)N + col] = (unsigned char)(p01 & 0xff);
        o8[(rbase + 1) * (long)N + col] = (unsigned char)((p01 >> 8) & 0xff);
        o8[(rbase + 2) * (long)N + col] = (unsigned char)(p23 & 0xff);
        o8[(rbase + 3) * (long)N + col] = (unsigned char)((p23 >> 8) & 0xff);
      } else {
#pragma unroll
        for (int r = 0; r < 4; ++r) {
          const long idx = (rbase + r) * (long)N + col;
          ((float*)outp)[idx] = acc[m][n][r] + bv + bf2f(resid[idx]);
        }
      }
    }
  }
}

// ---------------------------------------------------------------- attention
__global__ __launch_bounds__(256)
void attn_win(const unsigned short* __restrict__ qx_,
              const unsigned short* __restrict__ kvx_,
              unsigned short* __restrict__ ox_,
              const unsigned short* __restrict__ qy_,
              const unsigned short* __restrict__ kvy_,
              unsigned short* __restrict__ oy_,
              const float* __restrict__ nmask,
              const float* __restrict__ rpb) {
  __shared__ float nm_s[64];
  __shared__ unsigned short rpb_s[3600];
  __shared__ unsigned short P_s[4][64][72];
  __shared__ unsigned short Vt_s[4][32][72];

  const unsigned short* qbuf; const unsigned short* kvbuf; unsigned short* obuf;
  if (blockIdx.y == 0) { qbuf = qy_; kvbuf = kvx_; obuf = ox_; }
  else                 { qbuf = qx_; kvbuf = kvy_; obuf = oy_; }

  const int tid = threadIdx.x;
  const int lane = tid & 63;
  const int wid = tid >> 6;
  const int wi = blockIdx.x;
  const int wbase = (wi >> 6) * 4096 + ((wi >> 3) & 7) * 512 + (wi & 7) * 8;

  if (tid < 64) nm_s[tid] = nmask[wbase + ((tid >> 3) << 6) + (tid & 7)];
  for (int i = tid; i < 3600; i += 256) rpb_s[i] = f2bf(rpb[i]);
  __syncthreads();

  const int r0 = (lane >> 4) * 4;
  const int cn = lane & 15;
  const int kb8 = (lane >> 4) * 8;

  for (int hh = 0; hh < 4; ++hh) {
    const int h = wid * 4 + hh;

    f32x4 s[4][4] = {};
    {
      bf16x8 qa[4], kb[4];
#pragma unroll
      for (int m = 0; m < 4; ++m) {
        const int r = m * 16 + cn;
        const long tok = wbase + ((r >> 3) << 6) + (r & 7);
        qa[m] = *(const bf16x8*)(qbuf + tok * 1536 + h * 32 + kb8);
      }
#pragma unroll
      for (int n = 0; n < 4; ++n) {
        const int c = n * 16 + cn;
        const long tok = wbase + ((c >> 3) << 6) + (c & 7);
        kb[n] = *(const bf16x8*)(kvbuf + tok * 1536 + h * 32 + kb8);
      }
#pragma unroll
      for (int m = 0; m < 4; ++m)
#pragma unroll
        for (int n = 0; n < 4; ++n)
          s[m][n] = __builtin_amdgcn_mfma_f32_16x16x32_bf16(qa[m], kb[n], s[m][n], 0, 0, 0);
    }

#pragma unroll
    for (int m = 0; m < 4; ++m) {
#pragma unroll
      for (int r = 0; r < 4; ++r) {
        const int q = m * 16 + r0 + r;
        const int qi = q >> 3, qj = q & 7;
        float rowv[4];
#pragma unroll
        for (int n = 0; n < 4; ++n) {
          const int k = n * 16 + cn;
          const int ki = k >> 3, kj = k & 7;
          const int ridx = (qi - ki + 7) * 15 + (qj - kj + 7);
          rowv[n] = s[m][n][r] + bf2f(rpb_s[ridx * 16 + h]) + nm_s[q] + nm_s[k];
        }
        float mx = fmaxf(fmaxf(rowv[0], rowv[1]), fmaxf(rowv[2], rowv[3]));
#pragma unroll
        for (int off = 8; off; off >>= 1) mx = fmaxf(mx, __shfl_xor(mx, off));
        float sum = 0.f;
#pragma unroll
        for (int n = 0; n < 4; ++n) { rowv[n] = __expf(rowv[n] - mx); sum += rowv[n]; }
#pragma unroll
        for (int off = 8; off; off >>= 1) sum += __shfl_xor(sum, off);
        const float inv = 1.0f / sum;
#pragma unroll
        for (int n = 0; n < 4; ++n) s[m][n][r] = rowv[n] * inv;
      }
    }

#pragma unroll
    for (int m = 0; m < 4; ++m)
#pragma unroll
      for (int n = 0; n < 4; ++n)
#pragma unroll
        for (int r = 0; r < 4; ++r)
          P_s[wid][m * 16 + r0 + r][n * 16 + cn] = f2bf(s[m][n][r]);

    {
      const long tok = wbase + ((lane >> 3) << 6) + (lane & 7);
      const unsigned short* vrow = kvbuf + tok * 1536 + 512 + h * 32;
#pragma unroll
      for (int j = 0; j < 4; ++j) {
        bf16x8 vv = *(const bf16x8*)(vrow + j * 8);
#pragma unroll
        for (int e = 0; e < 8; ++e)
          Vt_s[wid][j * 8 + e][lane] = (unsigned short)vv[e];
      }
    }

    f32x4 o[4][2] = {};
#pragma unroll
    for (int t = 0; t < 2; ++t) {
      bf16x8 paf[4], vb[2];
#pragma unroll
      for (int m = 0; m < 4; ++m)
        paf[m] = *(const bf16x8*)(&P_s[wid][m * 16 + cn][t * 32 + kb8]);
#pragma unroll
      for (int n = 0; n < 2; ++n)
        vb[n] = *(const bf16x8*)(&Vt_s[wid][n * 16 + cn][t * 32 + kb8]);
#pragma unroll
      for (int m = 0; m < 4; ++m)
#pragma unroll
        for (int n = 0; n < 2; ++n)
          o[m][n] = __builtin_amdgcn_mfma_f32_16x16x32_bf16(paf[m], vb[n], o[m][n], 0, 0, 0);
    }

#pragma unroll
    for (int m = 0; m < 4; ++m) {
#pragma unroll
      for (int r = 0; r < 4; ++r) {
        const int q = m * 16 + r0 + r;
        const long tok = wbase + ((q >> 3) << 6) + (q & 7);
#pragma unroll
        for (int n = 0; n < 2; ++n)
          obuf[tok * 512 + h * 32 + n * 16 + cn] = f2bf(o[m][n][r]);
      }
    }
  }
}

// ---------------------------------------------------------------- launch
extern "C" void kernel_launch(void* const* d_in, const int* in_sizes, int n_in,
                              void* d_out, int out_size, void* d_ws, size_t ws_size,
                              hipStream_t stream) {
  const float* x = (const float*)d_in[0];
  const float* y = (const float*)d_in[1];
  const float* nmk = (const float*)d_in[2];
  const float* rpb = (const float*)d_in[3];
  const float* g1 = (const float*)d_in[4];
  const float* b1 = (const float*)d_in[5];
  const float* g3 = (const float*)d_in[6];
  const float* b3 = (const float*)d_in[7];
  const float* w_qkv = (const float*)d_in[8];
  const float* b_qkv = (const float*)d_in[9];
  const float* w_qkv_y = (const float*)d_in[10];
  const float* b_qkv_y = (const float*)d_in[11];
  const float* w_qx = (const float*)d_in[12];
  const float* b_qx = (const float*)d_in[13];
  const float* w_qy = (const float*)d_in[14];
  const float* b_qy = (const float*)d_in[15];
  const float* w_proj = (const float*)d_in[16];
  const float* b_proj = (const float*)d_in[17];
  const float* w_proj_y = (const float*)d_in[18];
  const float* b_proj_y = (const float*)d_in[19];
  const float* g2 = (const float*)d_in[20];
  const float* b2 = (const float*)d_in[21];
  const float* g4 = (const float*)d_in[22];
  const float* b4 = (const float*)d_in[23];
  const float* w_fc1 = (const float*)d_in[24];
  const float* b_fc1 = (const float*)d_in[25];
  const float* w_fc2 = (const float*)d_in[26];
  const float* b_fc2 = (const float*)d_in[27];
  const float* w_fc1y = (const float*)d_in[28];
  const float* b_fc1y = (const float*)d_in[29];
  const float* w_fc2y = (const float*)d_in[30];
  const float* b_fc2y = (const float*)d_in[31];

  char* ws = (char*)d_ws;
  unsigned short* wT_kvq_x = (unsigned short*)(ws + 0);          // 1536x512
  unsigned short* wT_kvq_y = (unsigned short*)(ws + 1572864);
  unsigned short* w_projT  = (unsigned short*)(ws + 3145728);
  unsigned short* w_projyT = (unsigned short*)(ws + 3670016);
  unsigned char*  w_fc1T8  = (unsigned char*)(ws + 4194304);     // 2048x512 fp8
  unsigned char*  w_fc2T8  = (unsigned char*)(ws + 6291456);     // 512x2048 fp8
  unsigned char*  w_fc1yT8 = (unsigned char*)(ws + 8388608);
  unsigned char*  w_fc2yT8 = (unsigned char*)(ws + 10485760);
  float* bias_kvq_x = (float*)(ws + 12582912);
  float* bias_kvq_y = (float*)(ws + 12589056);
  // XBF/YBF live steps 2-5, inside HBUF_X8's region (HBUF written step 7).
  unsigned short* XBF  = (unsigned short*)(ws + 12595200);   // bf16 copy of x
  unsigned short* YBF  = (unsigned short*)(ws + 46149632);   // bf16 copy of y
  unsigned short* XLN  = (unsigned short*)(ws + 79704064);   // ln1; later attnout_x
  unsigned short* YLN  = (unsigned short*)(ws + 113258496);  // ln3; later attnout_y
  unsigned short* KVQX = (unsigned short*)(ws + 146812928);  // 32768x1536
  unsigned short* KVQY = (unsigned short*)(ws + 247476224);  // 32768x1536
  unsigned short* X1   = (unsigned short*)(ws + 348139520);  // x1 bf16
  unsigned short* Y1   = (unsigned short*)(ws + 381693952);  // y1 bf16
  unsigned char*  X2LN8  = (unsigned char*)KVQX;               // 32768x512 fp8
  unsigned char*  Y2LN8  = (unsigned char*)(ws + 180367360);
  unsigned char*  HBUF_X8 = (unsigned char*)(ws + 12595200);   // 32768x2048 fp8
  unsigned char*  HBUF_Y8 = (unsigned char*)(ws + 213921792);

  float* out_x = (float*)d_out;
  float* out_y = out_x + 16777216;

  // 1. weight transposes
  {
    TpArgs ta{{w_qkv, w_qkv_y, nullptr, nullptr},
              {wT_kvq_x, wT_kvq_y, nullptr, nullptr}};
    transpose_w<<<dim3(16, 8, 2), 256, 0, stream>>>(ta, 512, 1024);
  }
  {
    TpArgs ta{{w_qx, w_qy, w_proj, w_proj_y},
              {wT_kvq_x + 1024 * 512, wT_kvq_y + 1024 * 512, w_projT, w_projyT}};
    transpose_w<<<dim3(8, 8, 4), 256, 0, stream>>>(ta, 512, 512);
  }
  {
    Tp8Args ta{{w_fc1, w_fc1y, nullptr, nullptr},
               {w_fc1T8, w_fc1yT8, nullptr, nullptr}};
    transpose_w8<<<dim3(32, 8, 2), 256, 0, stream>>>(ta, 512, 2048);
  }
  {
    Tp8Args ta{{w_fc2, w_fc2y, nullptr, nullptr},
               {w_fc2T8, w_fc2yT8, nullptr, nullptr}};
    transpose_w8<<<dim3(8, 32, 2), 256, 0, stream>>>(ta, 2048, 512);
  }

  pack_bias<<<6, 256, 0, stream>>>(b_qkv, b_qx, b_qkv_y, b_qy,
                                   bias_kvq_x, bias_kvq_y);

  // 2. LN1 / LN3 (+ bf16 raw copies of x,y for the proj residual)
  ln_dual<<<dim3(8192, 2), 256, 0, stream>>>(x, y, g1, b1, g3, b3,
                                             XLN, YLN, XBF, YBF);

  // 3. fused kv|q projections (bf16)
  const float qscale = 0.17677669529663687f;  // 1/sqrt(32)
  {
    PairArgs pa{XLN, YLN, wT_kvq_x, wT_kvq_y, bias_kvq_x, bias_kvq_y,
                nullptr, nullptr, KVQX, KVQY};
    gemm_mt<4><<<dim3(12, 128, 2), 512, 0, stream>>>(pa, qscale, NTOK, 1536, 512);
  }

  // 4. windowed attention
  attn_win<<<dim3(512, 2), 256, 0, stream>>>(KVQX + 1024, KVQX, XLN,
                                             KVQY + 1024, KVQY, YLN, nmk, rpb);

  // 5. proj + bf16 residual -> X1/Y1 (bf16)
  {
    PairArgs pa{XLN, YLN, w_projT, w_projyT, b_proj, b_proj_y, XBF, YBF, X1, Y1};
    gemm_mt<5><<<dim3(4, 128, 2), 512, 0, stream>>>(pa, 1.f, NTOK, 512, 512);
  }

  // 6. LN2 / LN4 -> fp8 (into dead KVQ region)
  ln_b16_f8<<<dim3(8192, 2), 256, 0, stream>>>(X1, Y1, g2, b2, g4, b4,
                                               X2LN8, Y2LN8);

  // 7. fc1 (fp8 x fp8, BK=128) + GELU -> fp8 HBUF (XBF/YBF dead now)
  {
    PairArgs pa{X2LN8, Y2LN8, w_fc1T8, w_fc1yT8, b_fc1, b_fc1y,
                nullptr, nullptr, HBUF_X8, HBUF_Y8};
    gemm_f8<2><<<dim3(16, 128, 2), 512, 0, stream>>>(pa, NTOK, 2048, 512);
  }
  // 8. fc2 (fp8 x fp8) + bf16 residual -> f32 d_out
  {
    PairArgs pa{HBUF_X8, HBUF_Y8, w_fc2T8, w_fc2yT8, b_fc2, b_fc2y,
                X1, Y1, out_x, out_y};
    gemm_f8<6><<<dim3(4, 128, 2), 512, 0, stream>>>(pa, NTOK, 512, 2048);
  }
}

// Round 19
// 665.906 us; speedup vs baseline: 1.0408x; 1.0408x over previous
//
#include <hip/hip_runtime.h>

// MixTransformerBlock on MI355X (gfx950).
// FINAL (Round 19) = exact R17, the verified session-best: 667.7 us,
// absmax 0.078 (reproduced twice within ±1 us).
// Pipeline: bf16 256x128 A-dbuf counted-vmcnt GEMMs (kvq fused kv|q N=1536,
// proj+f32-resid), merged 2-side window attention with LDS rpb, fused LN
// kernels (LN2/4 emit fp8), fp8-e4m3 BK=128 MLP GEMMs (fc1 GELU->fp8 via
// v_cvt_pk_fp8_f32, fc2 + bf16 resid -> f32 out), T1 XCD swizzle + T2
// both-sides LDS swizzle throughout.

typedef __attribute__((ext_vector_type(8))) short bf16x8;
typedef __attribute__((ext_vector_type(4))) float f32x4;

#define NTOK 32768   // B * H * W
#define CDIM 512

__device__ __forceinline__ unsigned short f2bf(float f) {
  unsigned int u = __float_as_uint(f);
  u = (u + 0x7fffu + ((u >> 16) & 1u)) >> 16;   // RNE (inputs finite)
  return (unsigned short)u;
}
__device__ __forceinline__ float bf2f(unsigned short u) {
  return __uint_as_float(((unsigned int)u) << 16);
}

__device__ __forceinline__ void gload_lds16(const void* g, void* l) {
  __builtin_amdgcn_global_load_lds(
      (const __attribute__((address_space(1))) void*)g,
      (__attribute__((address_space(3))) void*)l, 16, 0, 0);
}

// ---------------------------------------------------------------- transpose
struct TpArgs { const float* W[4]; unsigned short* O[4]; };

__global__ __launch_bounds__(256)
void transpose_w(TpArgs ta, int K, int N) {
  __shared__ float tile[64][65];
  const float* __restrict__ W = ta.W[blockIdx.z];
  unsigned short* __restrict__ Wt = ta.O[blockIdx.z];
  const int n0 = blockIdx.x * 64, k0 = blockIdx.y * 64;
  const int c = threadIdx.x & 63, rb = threadIdx.x >> 6;
#pragma unroll
  for (int i = 0; i < 16; ++i) {
    int r = i * 4 + rb;
    tile[r][c] = W[(long)(k0 + r) * N + n0 + c];
  }
  __syncthreads();
#pragma unroll
  for (int i = 0; i < 16; ++i) {
    int rn = i * 4 + rb;
    Wt[(long)(n0 + rn) * K + k0 + c] = f2bf(tile[c][rn]);
  }
}

struct Tp8Args { const float* W[4]; unsigned char* O[4]; };

__global__ __launch_bounds__(256)
void transpose_w8(Tp8Args ta, int K, int N) {
  __shared__ float tile[64][65];
  const float* __restrict__ W = ta.W[blockIdx.z];
  unsigned char* __restrict__ Wt = ta.O[blockIdx.z];
  const int n0 = blockIdx.x * 64, k0 = blockIdx.y * 64;
  const int c = threadIdx.x & 63, rb = threadIdx.x >> 6;
#pragma unroll
  for (int i = 0; i < 16; ++i) {
    int r = i * 4 + rb;
    tile[r][c] = W[(long)(k0 + r) * N + n0 + c];
  }
  __syncthreads();
#pragma unroll
  for (int i = 0; i < 16; ++i) {
    int rn = i * 4 + rb;
    const float v = tile[c][rn];
    int p = __builtin_amdgcn_cvt_pk_fp8_f32(v, v, 0, false);
    Wt[(long)(n0 + rn) * K + k0 + c] = (unsigned char)(p & 0xff);
  }
}

// ---------------------------------------------------------------- bias pack
__global__ __launch_bounds__(256)
void pack_bias(const float* bkv0, const float* bq0,
               const float* bkv1, const float* bq1,
               float* o0, float* o1) {
  const int i = blockIdx.x * 256 + threadIdx.x;   // 0..1535
  o0[i] = (i < 1024) ? bkv0[i] : bq0[i - 1024];
  o1[i] = (i < 1024) ? bkv1[i] : bq1[i - 1024];
}

// ---------------------------------------------------------------- layernorms
__global__ __launch_bounds__(256)
void ln_f32(const float* X0, const float* X1,
            const float* g0_, const float* b0_,
            const float* g1_, const float* b1_,
            unsigned short* o0, unsigned short* o1) {
  const int zz = blockIdx.y;
  const float* __restrict__ X = zz ? X1 : X0;
  const float* __restrict__ g = zz ? g1_ : g0_;
  const float* __restrict__ b = zz ? b1_ : b0_;
  unsigned short* __restrict__ out = zz ? o1 : o0;

  const int lane = threadIdx.x & 63;
  const int wid = threadIdx.x >> 6;
  const long t = (long)blockIdx.x * 4 + wid;
  const float* x = X + t * CDIM + lane * 8;
  float4 v0 = *(const float4*)x;
  float4 v1 = *(const float4*)(x + 4);
  float s = v0.x + v0.y + v0.z + v0.w + v1.x + v1.y + v1.z + v1.w;
  float sq = v0.x * v0.x + v0.y * v0.y + v0.z * v0.z + v0.w * v0.w +
             v1.x * v1.x + v1.y * v1.y + v1.z * v1.z + v1.w * v1.w;
#pragma unroll
  for (int off = 32; off; off >>= 1) {
    s += __shfl_xor(s, off);
    sq += __shfl_xor(sq, off);
  }
  const float mean = s * (1.0f / 512.0f);
  const float var = sq * (1.0f / 512.0f) - mean * mean;
  const float rs = rsqrtf(var + 1e-4f);
  float4 g0 = *(const float4*)(g + lane * 8);
  float4 g1 = *(const float4*)(g + lane * 8 + 4);
  float4 b0 = *(const float4*)(b + lane * 8);
  float4 b1 = *(const float4*)(b + lane * 8 + 4);
  bf16x8 r;
  r[0] = (short)f2bf((v0.x - mean) * rs * g0.x + b0.x);
  r[1] = (short)f2bf((v0.y - mean) * rs * g0.y + b0.y);
  r[2] = (short)f2bf((v0.z - mean) * rs * g0.z + b0.z);
  r[3] = (short)f2bf((v0.w - mean) * rs * g0.w + b0.w);
  r[4] = (short)f2bf((v1.x - mean) * rs * g1.x + b1.x);
  r[5] = (short)f2bf((v1.y - mean) * rs * g1.y + b1.y);
  r[6] = (short)f2bf((v1.z - mean) * rs * g1.z + b1.z);
  r[7] = (short)f2bf((v1.w - mean) * rs * g1.w + b1.w);
  *(bf16x8*)(out + t * CDIM + lane * 8) = r;
}

// bf16 in -> LN fp8 out (for LN2/LN4 feeding the fp8 fc1)
__global__ __launch_bounds__(256)
void ln_b16_f8(const unsigned short* X0, const unsigned short* X1,
               const float* g0_, const float* b0_,
               const float* g1_, const float* b1_,
               unsigned char* o0, unsigned char* o1) {
  const int zz = blockIdx.y;
  const unsigned short* __restrict__ X = zz ? X1 : X0;
  const float* __restrict__ g = zz ? g1_ : g0_;
  const float* __restrict__ b = zz ? b1_ : b0_;
  unsigned char* __restrict__ out = zz ? o1 : o0;

  const int lane = threadIdx.x & 63;
  const int wid = threadIdx.x >> 6;
  const long t = (long)blockIdx.x * 4 + wid;
  bf16x8 v = *(const bf16x8*)(X + t * CDIM + lane * 8);
  float f[8];
  float s = 0.f, sq = 0.f;
#pragma unroll
  for (int i = 0; i < 8; ++i) {
    f[i] = bf2f((unsigned short)v[i]);
    s += f[i]; sq += f[i] * f[i];
  }
#pragma unroll
  for (int off = 32; off; off >>= 1) {
    s += __shfl_xor(s, off);
    sq += __shfl_xor(sq, off);
  }
  const float mean = s * (1.0f / 512.0f);
  const float var = sq * (1.0f / 512.0f) - mean * mean;
  const float rs = rsqrtf(var + 1e-4f);
  float4 g0 = *(const float4*)(g + lane * 8);
  float4 g1 = *(const float4*)(g + lane * 8 + 4);
  float4 b0 = *(const float4*)(b + lane * 8);
  float4 b1 = *(const float4*)(b + lane * 8 + 4);
  const float gg[8] = {g0.x, g0.y, g0.z, g0.w, g1.x, g1.y, g1.z, g1.w};
  const float bb[8] = {b0.x, b0.y, b0.z, b0.w, b1.x, b1.y, b1.z, b1.w};
  float q[8];
#pragma unroll
  for (int i = 0; i < 8; ++i)
    q[i] = (f[i] - mean) * rs * gg[i] + bb[i];
  int w0 = __builtin_amdgcn_cvt_pk_fp8_f32(q[0], q[1], 0, false);
  w0 = __builtin_amdgcn_cvt_pk_fp8_f32(q[2], q[3], w0, true);
  int w1 = __builtin_amdgcn_cvt_pk_fp8_f32(q[4], q[5], 0, false);
  w1 = __builtin_amdgcn_cvt_pk_fp8_f32(q[6], q[7], w1, true);
  int2 pk; pk.x = w0; pk.y = w1;
  *(int2*)(out + t * CDIM + lane * 8) = pk;
}

// ---------------------------------------------------------------- GEMM 256x128 (bf16, R11)
// EPI 4: out bf16 (+bias), * scale for cols >= 1024      (fused kv|q)
// EPI 5: out bf16 (+bias + f32 resid)                    (proj -> x1)

struct PairArgs {
  const void* A0; const void* A1;
  const void* B0; const void* B1;
  const float* bias0; const float* bias1;
  const void* r0; const void* r1;
  void* o0; void* o1;
};

template <int EPI>
__global__ __launch_bounds__(512, 4)
void gemm_mt(PairArgs pa, float scale, int M, int N, int K) {
  // LDS: A dbuf 2x32K | B 16K at 65536. Total 80 KB -> 2 blocks/CU.
  __shared__ __attribute__((aligned(16))) char lds[81920];

  const int z = blockIdx.z;
  const unsigned short* __restrict__ A  = (const unsigned short*)(z ? pa.A1 : pa.A0);
  const unsigned short* __restrict__ Bt = (const unsigned short*)(z ? pa.B1 : pa.B0);
  const float* __restrict__ bias = z ? pa.bias1 : pa.bias0;
  const void* resid = z ? pa.r1 : pa.r0;
  void* outp = z ? pa.o1 : pa.o0;

  // T1: bijective XCD-aware remap (m204 form)
  const int nwg = gridDim.x * gridDim.y;
  int wg = blockIdx.y * gridDim.x + blockIdx.x;
  {
    const int q8 = nwg >> 3, r8 = nwg & 7;
    const int xcd = wg & 7, o = wg >> 3;
    wg = (xcd < r8 ? xcd * (q8 + 1) : r8 * (q8 + 1) + (xcd - r8) * q8) + o;
  }
  const int bx = wg % gridDim.x, by = wg / gridDim.x;

  const int tid = threadIdx.x;
  const int lane = tid & 63;
  const int wid = tid >> 6;        // 0..7
  const int wr = wid >> 1;         // 0..3  (M quarter)
  const int wc = wid & 1;          // 0..1  (N half)
  const long rowBase = (long)by * 256;
  const long colBase = (long)bx * 128;

  const unsigned short* Ap = A + rowBase * K;
  const unsigned short* Bp = Bt + colBase * K;

  const int srow = tid >> 3;                     // 0..63
  const int sslot = (tid & 7) ^ (srow & 7);      // permuted 16B slot

  auto stA = [&](int buf, int k0, int i) {       // i = 0..3 (256 rows)
    gload_lds16(Ap + (long)(i * 64 + srow) * K + k0 + sslot * 8,
                lds + buf * 32768 + i * 8192 + tid * 16);
  };
  auto stB = [&](int k0, int i) {                // i = 0..1 (128 rows)
    gload_lds16(Bp + (long)(i * 64 + srow) * K + k0 + sslot * 8,
                lds + 65536 + i * 8192 + tid * 16);
  };

  const int lo = lane & 15;
  const int hi = lane >> 4;
  const int x7 = lane & 7;
  const int arow0 = (wr * 64 + lo) * 128;            // bytes within A buffer
  const int brow0 = 65536 + (wc * 64 + lo) * 128;    // bytes within B region

  f32x4 acc[4][4] = {};

  const int nt = K / 64;

  stA(0, 0, 0); stA(0, 0, 1); stA(0, 0, 2); stA(0, 0, 3);

  for (int t = 0; t < nt; ++t) {
    const int cur = t & 1;
    const int k0 = t * 64;
    const bool pf = (t + 1 < nt);

    stB(k0, 0); stB(k0, 1);
    if (pf) {
      const int k1 = k0 + 64;
      stA(cur ^ 1, k1, 0); stA(cur ^ 1, k1, 1);
      stA(cur ^ 1, k1, 2); stA(cur ^ 1, k1, 3);
      asm volatile("s_waitcnt vmcnt(4)" ::: "memory");   // A(t)+B(t) landed
    } else {
      asm volatile("s_waitcnt vmcnt(0)" ::: "memory");
    }
    __builtin_amdgcn_sched_barrier(0);
    __builtin_amdgcn_s_barrier();

#pragma unroll
    for (int kk = 0; kk < 2; ++kk) {
      const int cb = ((kk * 4 + hi) ^ x7) * 16;
      bf16x8 af[4], bf[4];
#pragma unroll
      for (int m = 0; m < 4; ++m)
        af[m] = *(const bf16x8*)(lds + cur * 32768 + arow0 + m * 2048 + cb);
#pragma unroll
      for (int n = 0; n < 4; ++n)
        bf[n] = *(const bf16x8*)(lds + brow0 + n * 2048 + cb);
#pragma unroll
      for (int m = 0; m < 4; ++m)
#pragma unroll
        for (int n = 0; n < 4; ++n)
          acc[m][n] = __builtin_amdgcn_mfma_f32_16x16x32_bf16(af[m], bf[n], acc[m][n], 0, 0, 0);
    }
    if (pf) __builtin_amdgcn_s_barrier();
  }

  // -------- epilogue
#pragma unroll
  for (int m = 0; m < 4; ++m) {
    const long rbase = rowBase + wr * 64 + m * 16 + hi * 4;
#pragma unroll
    for (int n = 0; n < 4; ++n) {
      const long col = colBase + wc * 64 + n * 16 + lo;
      const float bv = bias[col];
#pragma unroll
      for (int r = 0; r < 4; ++r) {
        float v = acc[m][n][r] + bv;
        const long idx = (rbase + r) * (long)N + col;
        if constexpr (EPI == 4) {
          if (col >= 1024) v *= scale;
          ((unsigned short*)outp)[idx] = f2bf(v);
        } else if constexpr (EPI == 5) {
          ((unsigned short*)outp)[idx] = f2bf(v + ((const float*)resid)[idx]);
        } else {
          ((unsigned short*)outp)[idx] = f2bf(v);
        }
      }
    }
  }
}

// ---------------------------------------------------------------- GEMM fp8
// BK=128, A-dbuf, R11 structure. ds_read = b64 (R15 form).
// EPI 2: out fp8 gelu_tanh(+bias)       (fc1)
// EPI 6: out f32 (+bias + bf16 resid)   (fc2)
template <int EPI>
__global__ __launch_bounds__(512, 4)
void gemm_f8(PairArgs pa, int M, int N, int K) {
  // LDS: A dbuf 2x32K | B 16K at 65536. 80 KB -> 2 blocks/CU.
  __shared__ __attribute__((aligned(16))) char lds[81920];

  const int z = blockIdx.z;
  const unsigned char* __restrict__ A  = (const unsigned char*)(z ? pa.A1 : pa.A0);
  const unsigned char* __restrict__ Bt = (const unsigned char*)(z ? pa.B1 : pa.B0);
  const float* __restrict__ bias = z ? pa.bias1 : pa.bias0;
  const unsigned short* __restrict__ resid =
      (const unsigned short*)(z ? pa.r1 : pa.r0);
  void* outp = z ? pa.o1 : pa.o0;

  const int nwg = gridDim.x * gridDim.y;
  int wg = blockIdx.y * gridDim.x + blockIdx.x;
  {
    const int q8 = nwg >> 3, r8 = nwg & 7;
    const int xcd = wg & 7, o = wg >> 3;
    wg = (xcd < r8 ? xcd * (q8 + 1) : r8 * (q8 + 1) + (xcd - r8) * q8) + o;
  }
  const int bx = wg % gridDim.x, by = wg / gridDim.x;

  const int tid = threadIdx.x;
  const int lane = tid & 63;
  const int wid = tid >> 6;
  const int wr = wid >> 1;         // 0..3
  const int wc = wid & 1;          // 0..1
  const long rowBase = (long)by * 256;
  const long colBase = (long)bx * 128;

  const unsigned char* Ap = A + rowBase * K;
  const unsigned char* Bp = Bt + colBase * K;

  const int srow = tid >> 3;                     // 0..63
  const int schunk = ((tid & 7) ^ (srow & 7)) * 16;   // byte offset in row

  auto stA = [&](int buf, int k0, int i) {       // i=0..3 (256 rows)
    gload_lds16(Ap + (long)(i * 64 + srow) * K + k0 + schunk,
                lds + buf * 32768 + i * 8192 + tid * 16);
  };
  auto stB = [&](int k0, int i) {                // i=0..1 (128 rows)
    gload_lds16(Bp + (long)(i * 64 + srow) * K + k0 + schunk,
                lds + 65536 + i * 8192 + tid * 16);
  };

  const int lo = lane & 15;
  const int hi = lane >> 4;
  const int arow0 = (wr * 64 + lo) * 128;
  const int brow0 = 65536 + (wc * 64 + lo) * 128;

  f32x4 acc[4][4] = {};

  const int nt = K / 128;

  stA(0, 0, 0); stA(0, 0, 1); stA(0, 0, 2); stA(0, 0, 3);

  for (int t = 0; t < nt; ++t) {
    const int cur = t & 1;
    const int k0 = t * 128;
    const bool pf = (t + 1 < nt);

    stB(k0, 0); stB(k0, 1);
    if (pf) {
      const int k1 = k0 + 128;
      stA(cur ^ 1, k1, 0); stA(cur ^ 1, k1, 1);
      stA(cur ^ 1, k1, 2); stA(cur ^ 1, k1, 3);
      asm volatile("s_waitcnt vmcnt(4)" ::: "memory");
    } else {
      asm volatile("s_waitcnt vmcnt(0)" ::: "memory");
    }
    __builtin_amdgcn_sched_barrier(0);
    __builtin_amdgcn_s_barrier();

#pragma unroll
    for (int kk = 0; kk < 4; ++kk) {
      // lane needs bytes [kk*32 + hi*8, +8) of its row, chunk-swizzled:
      const int cb = (((kk * 2 + (hi >> 1)) ^ (lo & 7)) * 16) + (hi & 1) * 8;
      long af[4], bq[4];
#pragma unroll
      for (int m = 0; m < 4; ++m)
        af[m] = *(const long*)(lds + cur * 32768 + arow0 + m * 2048 + cb);
#pragma unroll
      for (int n = 0; n < 4; ++n)
        bq[n] = *(const long*)(lds + brow0 + n * 2048 + cb);
#pragma unroll
      for (int m = 0; m < 4; ++m)
#pragma unroll
        for (int n = 0; n < 4; ++n)
          acc[m][n] = __builtin_amdgcn_mfma_f32_16x16x32_fp8_fp8(af[m], bq[n], acc[m][n], 0, 0, 0);
    }
    if (pf) __builtin_amdgcn_s_barrier();
  }

  // -------- epilogue
#pragma unroll
  for (int m = 0; m < 4; ++m) {
    const long rbase = rowBase + wr * 64 + m * 16 + hi * 4;
#pragma unroll
    for (int n = 0; n < 4; ++n) {
      const long col = colBase + wc * 64 + n * 16 + lo;
      const float bv = bias[col];
      if constexpr (EPI == 2) {
        float vv[4];
#pragma unroll
        for (int r = 0; r < 4; ++r) {
          float v = acc[m][n][r] + bv;
          const float tt = 1.5957691216057308f * v * (1.0f + 0.044715f * v * v);
          vv[r] = v * __fdividef(1.0f, 1.0f + __expf(-tt));
        }
        const int p01 = __builtin_amdgcn_cvt_pk_fp8_f32(vv[0], vv[1], 0, false);
        const int p23 = __builtin_amdgcn_cvt_pk_fp8_f32(vv[2], vv[3], 0, false);
        unsigned char* o8 = (unsigned char*)outp;
        o8[(rbase + 0) * (long)N + col] = (unsigned char)(p01 & 0xff);
        o8[(rbase + 1) * (long)N + col] = (unsigned char)((p01 >> 8) & 0xff);
        o8[(rbase + 2) * (long)N + col] = (unsigned char)(p23 & 0xff);
        o8[(rbase + 3) * (long)N + col] = (unsigned char)((p23 >> 8) & 0xff);
      } else {
#pragma unroll
        for (int r = 0; r < 4; ++r) {
          const long idx = (rbase + r) * (long)N + col;
          ((float*)outp)[idx] = acc[m][n][r] + bv + bf2f(resid[idx]);
        }
      }
    }
  }
}

// ---------------------------------------------------------------- attention
__global__ __launch_bounds__(256)
void attn_win(const unsigned short* __restrict__ qx_,
              const unsigned short* __restrict__ kvx_,
              unsigned short* __restrict__ ox_,
              const unsigned short* __restrict__ qy_,
              const unsigned short* __restrict__ kvy_,
              unsigned short* __restrict__ oy_,
              const float* __restrict__ nmask,
              const float* __restrict__ rpb) {
  __shared__ float nm_s[64];
  __shared__ unsigned short rpb_s[3600];
  __shared__ unsigned short P_s[4][64][72];
  __shared__ unsigned short Vt_s[4][32][72];

  const unsigned short* qbuf; const unsigned short* kvbuf; unsigned short* obuf;
  if (blockIdx.y == 0) { qbuf = qy_; kvbuf = kvx_; obuf = ox_; }
  else                 { qbuf = qx_; kvbuf = kvy_; obuf = oy_; }

  const int tid = threadIdx.x;
  const int lane = tid & 63;
  const int wid = tid >> 6;
  const int wi = blockIdx.x;
  const int wbase = (wi >> 6) * 4096 + ((wi >> 3) & 7) * 512 + (wi & 7) * 8;

  if (tid < 64) nm_s[tid] = nmask[wbase + ((tid >> 3) << 6) + (tid & 7)];
  for (int i = tid; i < 3600; i += 256) rpb_s[i] = f2bf(rpb[i]);
  __syncthreads();

  const int r0 = (lane >> 4) * 4;
  const int cn = lane & 15;
  const int kb8 = (lane >> 4) * 8;

  for (int hh = 0; hh < 4; ++hh) {
    const int h = wid * 4 + hh;

    f32x4 s[4][4] = {};
    {
      bf16x8 qa[4], kb[4];
#pragma unroll
      for (int m = 0; m < 4; ++m) {
        const int r = m * 16 + cn;
        const long tok = wbase + ((r >> 3) << 6) + (r & 7);
        qa[m] = *(const bf16x8*)(qbuf + tok * 1536 + h * 32 + kb8);
      }
#pragma unroll
      for (int n = 0; n < 4; ++n) {
        const int c = n * 16 + cn;
        const long tok = wbase + ((c >> 3) << 6) + (c & 7);
        kb[n] = *(const bf16x8*)(kvbuf + tok * 1536 + h * 32 + kb8);
      }
#pragma unroll
      for (int m = 0; m < 4; ++m)
#pragma unroll
        for (int n = 0; n < 4; ++n)
          s[m][n] = __builtin_amdgcn_mfma_f32_16x16x32_bf16(qa[m], kb[n], s[m][n], 0, 0, 0);
    }

#pragma unroll
    for (int m = 0; m < 4; ++m) {
#pragma unroll
      for (int r = 0; r < 4; ++r) {
        const int q = m * 16 + r0 + r;
        const int qi = q >> 3, qj = q & 7;
        float rowv[4];
#pragma unroll
        for (int n = 0; n < 4; ++n) {
          const int k = n * 16 + cn;
          const int ki = k >> 3, kj = k & 7;
          const int ridx = (qi - ki + 7) * 15 + (qj - kj + 7);
          rowv[n] = s[m][n][r] + bf2f(rpb_s[ridx * 16 + h]) + nm_s[q] + nm_s[k];
        }
        float mx = fmaxf(fmaxf(rowv[0], rowv[1]), fmaxf(rowv[2], rowv[3]));
#pragma unroll
        for (int off = 8; off; off >>= 1) mx = fmaxf(mx, __shfl_xor(mx, off));
        float sum = 0.f;
#pragma unroll
        for (int n = 0; n < 4; ++n) { rowv[n] = __expf(rowv[n] - mx); sum += rowv[n]; }
#pragma unroll
        for (int off = 8; off; off >>= 1) sum += __shfl_xor(sum, off);
        const float inv = 1.0f / sum;
#pragma unroll
        for (int n = 0; n < 4; ++n) s[m][n][r] = rowv[n] * inv;
      }
    }

#pragma unroll
    for (int m = 0; m < 4; ++m)
#pragma unroll
      for (int n = 0; n < 4; ++n)
#pragma unroll
        for (int r = 0; r < 4; ++r)
          P_s[wid][m * 16 + r0 + r][n * 16 + cn] = f2bf(s[m][n][r]);

    {
      const long tok = wbase + ((lane >> 3) << 6) + (lane & 7);
      const unsigned short* vrow = kvbuf + tok * 1536 + 512 + h * 32;
#pragma unroll
      for (int j = 0; j < 4; ++j) {
        bf16x8 vv = *(const bf16x8*)(vrow + j * 8);
#pragma unroll
        for (int e = 0; e < 8; ++e)
          Vt_s[wid][j * 8 + e][lane] = (unsigned short)vv[e];
      }
    }

    f32x4 o[4][2] = {};
#pragma unroll
    for (int t = 0; t < 2; ++t) {
      bf16x8 paf[4], vb[2];
#pragma unroll
      for (int m = 0; m < 4; ++m)
        paf[m] = *(const bf16x8*)(&P_s[wid][m * 16 + cn][t * 32 + kb8]);
#pragma unroll
      for (int n = 0; n < 2; ++n)
        vb[n] = *(const bf16x8*)(&Vt_s[wid][n * 16 + cn][t * 32 + kb8]);
#pragma unroll
      for (int m = 0; m < 4; ++m)
#pragma unroll
        for (int n = 0; n < 2; ++n)
          o[m][n] = __builtin_amdgcn_mfma_f32_16x16x32_bf16(paf[m], vb[n], o[m][n], 0, 0, 0);
    }

#pragma unroll
    for (int m = 0; m < 4; ++m) {
#pragma unroll
      for (int r = 0; r < 4; ++r) {
        const int q = m * 16 + r0 + r;
        const long tok = wbase + ((q >> 3) << 6) + (q & 7);
#pragma unroll
        for (int n = 0; n < 2; ++n)
          obuf[tok * 512 + h * 32 + n * 16 + cn] = f2bf(o[m][n][r]);
      }
    }
  }
}

// ---------------------------------------------------------------- launch
extern "C" void kernel_launch(void* const* d_in, const int* in_sizes, int n_in,
                              void* d_out, int out_size, void* d_ws, size_t ws_size,
                              hipStream_t stream) {
  const float* x = (const float*)d_in[0];
  const float* y = (const float*)d_in[1];
  const float* nmk = (const float*)d_in[2];
  const float* rpb = (const float*)d_in[3];
  const float* g1 = (const float*)d_in[4];
  const float* b1 = (const float*)d_in[5];
  const float* g3 = (const float*)d_in[6];
  const float* b3 = (const float*)d_in[7];
  const float* w_qkv = (const float*)d_in[8];
  const float* b_qkv = (const float*)d_in[9];
  const float* w_qkv_y = (const float*)d_in[10];
  const float* b_qkv_y = (const float*)d_in[11];
  const float* w_qx = (const float*)d_in[12];
  const float* b_qx = (const float*)d_in[13];
  const float* w_qy = (const float*)d_in[14];
  const float* b_qy = (const float*)d_in[15];
  const float* w_proj = (const float*)d_in[16];
  const float* b_proj = (const float*)d_in[17];
  const float* w_proj_y = (const float*)d_in[18];
  const float* b_proj_y = (const float*)d_in[19];
  const float* g2 = (const float*)d_in[20];
  const float* b2 = (const float*)d_in[21];
  const float* g4 = (const float*)d_in[22];
  const float* b4 = (const float*)d_in[23];
  const float* w_fc1 = (const float*)d_in[24];
  const float* b_fc1 = (const float*)d_in[25];
  const float* w_fc2 = (const float*)d_in[26];
  const float* b_fc2 = (const float*)d_in[27];
  const float* w_fc1y = (const float*)d_in[28];
  const float* b_fc1y = (const float*)d_in[29];
  const float* w_fc2y = (const float*)d_in[30];
  const float* b_fc2y = (const float*)d_in[31];

  char* ws = (char*)d_ws;
  unsigned short* wT_kvq_x = (unsigned short*)(ws + 0);          // 1536x512
  unsigned short* wT_kvq_y = (unsigned short*)(ws + 1572864);
  unsigned short* w_projT  = (unsigned short*)(ws + 3145728);
  unsigned short* w_projyT = (unsigned short*)(ws + 3670016);
  unsigned char*  w_fc1T8  = (unsigned char*)(ws + 4194304);     // 2048x512 fp8
  unsigned char*  w_fc2T8  = (unsigned char*)(ws + 6291456);     // 512x2048 fp8
  unsigned char*  w_fc1yT8 = (unsigned char*)(ws + 8388608);
  unsigned char*  w_fc2yT8 = (unsigned char*)(ws + 10485760);
  float* bias_kvq_x = (float*)(ws + 12582912);
  float* bias_kvq_y = (float*)(ws + 12589056);
  unsigned short* XLN  = (unsigned short*)(ws + 79704064);   // ln1; later attnout_x
  unsigned short* YLN  = (unsigned short*)(ws + 113258496);  // ln3; later attnout_y
  unsigned short* KVQX = (unsigned short*)(ws + 146812928);  // 32768x1536
  unsigned short* KVQY = (unsigned short*)(ws + 247476224);  // 32768x1536
  unsigned short* X1   = (unsigned short*)(ws + 348139520);  // x1 bf16
  unsigned short* Y1   = (unsigned short*)(ws + 381693952);  // y1 bf16
  unsigned char*  X2LN8  = (unsigned char*)KVQX;               // 32768x512 fp8
  unsigned char*  Y2LN8  = (unsigned char*)(ws + 180367360);
  unsigned char*  HBUF_X8 = (unsigned char*)(ws + 12595200);   // 32768x2048 fp8
  unsigned char*  HBUF_Y8 = (unsigned char*)(ws + 213921792);

  float* out_x = (float*)d_out;
  float* out_y = out_x + 16777216;

  // 1. weight transposes
  {
    TpArgs ta{{w_qkv, w_qkv_y, nullptr, nullptr},
              {wT_kvq_x, wT_kvq_y, nullptr, nullptr}};
    transpose_w<<<dim3(16, 8, 2), 256, 0, stream>>>(ta, 512, 1024);
  }
  {
    TpArgs ta{{w_qx, w_qy, w_proj, w_proj_y},
              {wT_kvq_x + 1024 * 512, wT_kvq_y + 1024 * 512, w_projT, w_projyT}};
    transpose_w<<<dim3(8, 8, 4), 256, 0, stream>>>(ta, 512, 512);
  }
  {
    Tp8Args ta{{w_fc1, w_fc1y, nullptr, nullptr},
               {w_fc1T8, w_fc1yT8, nullptr, nullptr}};
    transpose_w8<<<dim3(32, 8, 2), 256, 0, stream>>>(ta, 512, 2048);
  }
  {
    Tp8Args ta{{w_fc2, w_fc2y, nullptr, nullptr},
               {w_fc2T8, w_fc2yT8, nullptr, nullptr}};
    transpose_w8<<<dim3(8, 32, 2), 256, 0, stream>>>(ta, 2048, 512);
  }

  pack_bias<<<6, 256, 0, stream>>>(b_qkv, b_qx, b_qkv_y, b_qy,
                                   bias_kvq_x, bias_kvq_y);

  // 2. LN1 / LN3
  ln_f32<<<dim3(8192, 2), 256, 0, stream>>>(x, y, g1, b1, g3, b3, XLN, YLN);

  // 3. fused kv|q projections (bf16)
  const float qscale = 0.17677669529663687f;  // 1/sqrt(32)
  {
    PairArgs pa{XLN, YLN, wT_kvq_x, wT_kvq_y, bias_kvq_x, bias_kvq_y,
                nullptr, nullptr, KVQX, KVQY};
    gemm_mt<4><<<dim3(12, 128, 2), 512, 0, stream>>>(pa, qscale, NTOK, 1536, 512);
  }

  // 4. windowed attention
  attn_win<<<dim3(512, 2), 256, 0, stream>>>(KVQX + 1024, KVQX, XLN,
                                             KVQY + 1024, KVQY, YLN, nmk, rpb);

  // 5. proj + f32 residual -> X1/Y1 (bf16)
  {
    PairArgs pa{XLN, YLN, w_projT, w_projyT, b_proj, b_proj_y, x, y, X1, Y1};
    gemm_mt<5><<<dim3(4, 128, 2), 512, 0, stream>>>(pa, 1.f, NTOK, 512, 512);
  }

  // 6. LN2 / LN4 -> fp8 (into dead KVQ region)
  ln_b16_f8<<<dim3(8192, 2), 256, 0, stream>>>(X1, Y1, g2, b2, g4, b4,
                                               X2LN8, Y2LN8);

  // 7. fc1 (fp8 x fp8, BK=128) + GELU -> fp8 HBUF
  {
    PairArgs pa{X2LN8, Y2LN8, w_fc1T8, w_fc1yT8, b_fc1, b_fc1y,
                nullptr, nullptr, HBUF_X8, HBUF_Y8};
    gemm_f8<2><<<dim3(16, 128, 2), 512, 0, stream>>>(pa, NTOK, 2048, 512);
  }
  // 8. fc2 (fp8 x fp8) + bf16 residual -> f32 d_out
  {
    PairArgs pa{HBUF_X8, HBUF_Y8, w_fc2T8, w_fc2yT8, b_fc2, b_fc2y,
                X1, Y1, out_x, out_y};
    gemm_f8<6><<<dim3(4, 128, 2), 512, 0, stream>>>(pa, NTOK, 512, 2048);
  }
}